// Round 1
// baseline (470.735 us; speedup 1.0000x reference)
//
#include <hip/hip_runtime.h>
#include <stdint.h>
#include <stddef.h>

// Problem constants (MultiHeadAttention_52759378264454)
constexpr int T_SEQ = 1024;
constexpr int BATCH = 8;
constexpr int DIN   = 256;
constexpr int NH    = 8;
constexpr int EH    = 512;
constexpr float SCALE = 0.044194173824159216f; // 1/sqrt(512)

typedef __attribute__((ext_vector_type(8))) short s16x8;
typedef __attribute__((ext_vector_type(4))) short s16x4;
typedef __attribute__((ext_vector_type(4))) float f32x4_t;

__device__ __forceinline__ short f2bf(float f) {
  union { float f; uint32_t u; } c; c.f = f;
  uint32_t u = c.u;
  u += 0x7fffu + ((u >> 16) & 1u);   // RNE (finite values only here)
  return (short)(u >> 16);
}
__device__ __forceinline__ float bf2f(short s) {
  union { uint32_t u; float f; } c; c.u = ((uint32_t)(uint16_t)s) << 16;
  return c.f;
}

// async global->LDS, 16B per lane. LDS dest must be wave-uniform base (+lane*16 by HW).
__device__ __forceinline__ void gload16(const short* g, short* l) {
  __builtin_amdgcn_global_load_lds(
      (__attribute__((address_space(1))) void*)(void*)const_cast<short*>(g),
      (__attribute__((address_space(3))) void*)(void*)l, 16, 0, 0);
}

// ---------------------------------------------------------------------------
// Core K-loop: C[BM,BN] += A[BM,K] * B[BN,K]^T, A/B both K-major bf16.
// BM = MI*32, BN = NI*32. 256 threads = 4 waves in 2x2 (wm, wn).
// LDS tiles As[BM][64], Bs[BN][64], single-buffered, 2 barriers / K-step.
// MFMA 16x16x32 bf16: A-frag lane l: row=l&15, k=(l>>4)*8+j (contig 8);
// C/D: col=l&15, row=(l>>4)*4+reg.
// ---------------------------------------------------------------------------
template<int MI, int NI>
__device__ __forceinline__ void gemm_core(const short* __restrict__ Ag, int lda,
                                          const short* __restrict__ Bg, int ldb,
                                          int K, short* As, short* Bs,
                                          f32x4_t (&acc)[MI][NI])
{
  const int tid  = threadIdx.x;
  const int lane = tid & 63;
  const int wv   = tid >> 6;
  const int wm   = wv >> 1, wn = wv & 1;
  const int g    = lane >> 4, r = lane & 15;

  for (int kt = 0; kt < K; kt += 64) {
    __syncthreads();  // previous compute done before restaging
#pragma unroll
    for (int it = 0; it < MI; ++it) {          // MI == BM/32 staging rounds
      int slot = it * 256 + tid;               // 16B slots; 8 slots per 64-elem row
      int row  = slot >> 3;
      int col  = (slot & 7) << 3;
      gload16(Ag + (size_t)row * lda + kt + col,
              As + (size_t)(it * 256 + wv * 64) * 8);
    }
#pragma unroll
    for (int it = 0; it < NI; ++it) {
      int slot = it * 256 + tid;
      int row  = slot >> 3;
      int col  = (slot & 7) << 3;
      gload16(Bg + (size_t)row * ldb + kt + col,
              Bs + (size_t)(it * 256 + wv * 64) * 8);
    }
    __syncthreads();  // compiler emits vmcnt(0) drain here
#pragma unroll
    for (int kk = 0; kk < 64; kk += 32) {
      s16x8 af[MI], bfr[NI];
#pragma unroll
      for (int mi = 0; mi < MI; ++mi)
        af[mi] = *(const s16x8*)(As + (size_t)(wm * MI * 16 + mi * 16 + r) * 64 + kk + g * 8);
#pragma unroll
      for (int ni = 0; ni < NI; ++ni)
        bfr[ni] = *(const s16x8*)(Bs + (size_t)(wn * NI * 16 + ni * 16 + r) * 64 + kk + g * 8);
#pragma unroll
      for (int mi = 0; mi < MI; ++mi)
#pragma unroll
        for (int ni = 0; ni < NI; ++ni)
          acc[mi][ni] = __builtin_amdgcn_mfma_f32_16x16x32_bf16(af[mi], bfr[ni], acc[mi][ni], 0, 0, 0);
    }
  }
}

// ---------------------------------------------------------------------------
// K0: fp32 -> bf16 cast (4 elems/thread, grid-stride)
// ---------------------------------------------------------------------------
__global__ __launch_bounds__(256) void k_cvt(const float* __restrict__ s,
                                             short* __restrict__ d, int n4)
{
  int i  = blockIdx.x * blockDim.x + threadIdx.x;
  int st = gridDim.x * blockDim.x;
  for (; i < n4; i += st) {
    float4 v = ((const float4*)s)[i];
    s16x4 o = { f2bf(v.x), f2bf(v.y), f2bf(v.z), f2bf(v.w) };
    ((s16x4*)d)[i] = o;
  }
}

// ---------------------------------------------------------------------------
// K1: QKV projection.  C[m=(t*B+b), e] = sum_d Qb[m,d] * W[h,e,d] + bias[h,e]
// grid (M/128=64, E/128=4, 3*HG);  out layout [hh][b][t][e] bf16
// ---------------------------------------------------------------------------
__global__ __launch_bounds__(256) void k_proj(
    const short* __restrict__ Qb,
    const short* __restrict__ Wqb, const short* __restrict__ Wkb, const short* __restrict__ Wvb,
    const float* __restrict__ bq, const float* __restrict__ bk, const float* __restrict__ bv,
    short* __restrict__ qb, short* __restrict__ kb, short* __restrict__ vb,
    int h0, int HG)
{
  __shared__ short As[128 * 64];
  __shared__ short Bs[128 * 64];
  const int bx = blockIdx.x, by = blockIdx.y, bz = blockIdx.z;
  const int p = bz / HG, hh = bz % HG, h = h0 + hh;

  const short* W    = (p == 0 ? Wqb : p == 1 ? Wkb : Wvb) + ((size_t)h * EH + (size_t)by * 128) * DIN;
  const float* bias = (p == 0 ? bq  : p == 1 ? bk  : bv ) + h * EH + by * 128;
  short* outp       = (p == 0 ? qb  : p == 1 ? kb  : vb ) + (size_t)hh * BATCH * T_SEQ * EH;
  const short* Ag   = Qb + (size_t)bx * 128 * DIN;

  f32x4_t acc[4][4] = {};
  gemm_core<4, 4>(Ag, DIN, W, DIN, DIN, As, Bs, acc);

  const int lane = threadIdx.x & 63, wv = threadIdx.x >> 6;
  const int wm = wv >> 1, wn = wv & 1, g = lane >> 4, r = lane & 15;
#pragma unroll
  for (int ni = 0; ni < 4; ++ni) {
    int coll = wn * 64 + ni * 16 + r;
    float bia = bias[coll];
    int e = by * 128 + coll;
#pragma unroll
    for (int mi = 0; mi < 4; ++mi) {
#pragma unroll
      for (int reg = 0; reg < 4; ++reg) {
        int m = bx * 128 + wm * 64 + mi * 16 + g * 4 + reg;
        int t = m >> 3, b = m & 7;
        outp[((size_t)(b * T_SEQ + t)) * EH + e] = f2bf(acc[mi][ni][reg] + bia);
      }
    }
  }
}

// ---------------------------------------------------------------------------
// K3a: P[t,s] = exp(SCALE * q.k) (bf16, unnormalized) + per-block column sums
// grid (T/128=8 t-tiles, T/128=8 s-tiles, HG*8);  z = hh*8+b
// colpart[(z*8 + t_tile)*T + s] = sum over this block's 128 t of exp
// ---------------------------------------------------------------------------
__global__ __launch_bounds__(256) void k_pgen(
    const short* __restrict__ qb, const short* __restrict__ kb,
    short* __restrict__ Pbuf, float* __restrict__ colpart)
{
  __shared__ short As[128 * 64];
  __shared__ short Bs[128 * 64];
  __shared__ float csL[2][128];
  const int bx = blockIdx.x, by = blockIdx.y;
  const int z = blockIdx.z;
  const short* Ag = qb + (size_t)z * T_SEQ * EH + (size_t)bx * 128 * EH;
  const short* Bg = kb + (size_t)z * T_SEQ * EH + (size_t)by * 128 * EH;

  f32x4_t acc[4][4] = {};
  gemm_core<4, 4>(Ag, EH, Bg, EH, EH, As, Bs, acc);

  short* Pb = Pbuf + (size_t)z * T_SEQ * T_SEQ;
  const int lane = threadIdx.x & 63, wv = threadIdx.x >> 6;
  const int wm = wv >> 1, wn = wv & 1, g = lane >> 4, r = lane & 15;

  float cs[4] = {0.f, 0.f, 0.f, 0.f};
#pragma unroll
  for (int ni = 0; ni < 4; ++ni) {
    int s = by * 128 + wn * 64 + ni * 16 + r;
#pragma unroll
    for (int mi = 0; mi < 4; ++mi) {
#pragma unroll
      for (int reg = 0; reg < 4; ++reg) {
        int t = bx * 128 + wm * 64 + mi * 16 + g * 4 + reg;
        float ev = __expf(acc[mi][ni][reg] * SCALE);
        cs[ni] += ev;
        Pb[(size_t)t * T_SEQ + s] = f2bf(ev);
      }
    }
  }
  // column partial sums: reduce over g groups (rows), then across wm via LDS
#pragma unroll
  for (int ni = 0; ni < 4; ++ni) {
    cs[ni] += __shfl_xor(cs[ni], 16);
    cs[ni] += __shfl_xor(cs[ni], 32);
  }
  if (g == 0) {
#pragma unroll
    for (int ni = 0; ni < 4; ++ni) csL[wm][wn * 64 + ni * 16 + r] = cs[ni];
  }
  __syncthreads();
  if (threadIdx.x < 128) {
    float tot = csL[0][threadIdx.x] + csL[1][threadIdx.x];
    colpart[((size_t)z * 8 + bx) * T_SEQ + by * 128 + threadIdx.x] = tot;
  }
}

// ---------------------------------------------------------------------------
// K2': inv colsum.  invs[z*T + s] = 1 / sum_tt colpart[(z*8+tt)*T + s]
// ---------------------------------------------------------------------------
__global__ __launch_bounds__(256) void k_invsum(const float* __restrict__ colpart,
                                                float* __restrict__ invs, int HB)
{
  int i = blockIdx.x * 256 + threadIdx.x;
  if (i < HB * T_SEQ) {
    int hb = i >> 10, s = i & (T_SEQ - 1);
    float sum = 0.f;
#pragma unroll
    for (int tt = 0; tt < 8; ++tt) sum += colpart[((size_t)hb * 8 + tt) * T_SEQ + s];
    invs[i] = 1.0f / sum;
  }
}

// ---------------------------------------------------------------------------
// K_tr: vbT[z][e][s] = vb[z][s][e] * invs[z][s]   (64x64 tiles via LDS)
// grid (T/64=16, E/64=8, HG*8)
// ---------------------------------------------------------------------------
__global__ __launch_bounds__(256) void k_tr(const short* __restrict__ vb,
                                            const float* __restrict__ invs,
                                            short* __restrict__ vbT)
{
  __shared__ float tl[64][65];
  const int bx = blockIdx.x, by = blockIdx.y, z = blockIdx.z;
  const short* in  = vb  + (size_t)z * T_SEQ * EH;
  short*       out = vbT + (size_t)z * EH * T_SEQ;
  const float* inv = invs + (size_t)z * T_SEQ;
  const int tid = threadIdx.x;

#pragma unroll
  for (int rep = 0; rep < 2; ++rep) {
    int s_l = (tid >> 3) + rep * 32;
    int e_l = (tid & 7) * 8;
    s16x8 v = *(const s16x8*)&in[(size_t)(bx * 64 + s_l) * EH + by * 64 + e_l];
    float iv = inv[bx * 64 + s_l];
#pragma unroll
    for (int j = 0; j < 8; ++j) tl[s_l][e_l + j] = bf2f(v[j]) * iv;
  }
  __syncthreads();
#pragma unroll
  for (int rep = 0; rep < 2; ++rep) {
    int e_w = (tid >> 3) + rep * 32;
    int s_w = (tid & 7) * 8;
    s16x8 o;
#pragma unroll
    for (int j = 0; j < 8; ++j) o[j] = f2bf(tl[s_w + j][e_w]);
    *(s16x8*)&out[(size_t)(by * 64 + e_w) * T_SEQ + bx * 64 + s_w] = o;
  }
}

// ---------------------------------------------------------------------------
// K3b: O[t,e] = sum_s P[t,s] * vbT[e,s]  -> Hmat[t, b, h*EH + e] (bf16)
// grid (T/128=8, E/128=4, HG*8)
// ---------------------------------------------------------------------------
__global__ __launch_bounds__(256) void k_ogemm(
    const short* __restrict__ Pbuf, const short* __restrict__ vbT,
    short* __restrict__ Hmat, int h0)
{
  __shared__ short As[128 * 64];
  __shared__ short Bs[128 * 64];
  const int bx = blockIdx.x, by = blockIdx.y, z = blockIdx.z;
  const short* Ag = Pbuf + (size_t)z * T_SEQ * T_SEQ + (size_t)bx * 128 * T_SEQ;
  const short* Bg = vbT  + (size_t)z * EH * T_SEQ    + (size_t)by * 128 * T_SEQ;

  f32x4_t acc[4][4] = {};
  gemm_core<4, 4>(Ag, T_SEQ, Bg, T_SEQ, T_SEQ, As, Bs, acc);

  const int hh = z >> 3, b = z & 7, h = h0 + hh;
  const int lane = threadIdx.x & 63, wv = threadIdx.x >> 6;
  const int wm = wv >> 1, wn = wv & 1, g = lane >> 4, r = lane & 15;
#pragma unroll
  for (int ni = 0; ni < 4; ++ni) {
    int e = by * 128 + wn * 64 + ni * 16 + r;
#pragma unroll
    for (int mi = 0; mi < 4; ++mi) {
#pragma unroll
      for (int reg = 0; reg < 4; ++reg) {
        int t = bx * 128 + wm * 64 + mi * 16 + g * 4 + reg;
        Hmat[((size_t)t * BATCH + b) * (NH * EH) + (size_t)h * EH + e] = f2bf(acc[mi][ni][reg]);
      }
    }
  }
}

// ---------------------------------------------------------------------------
// K4: out[m, d] = sum_he Hmat[m, he] * Wo[d, he] + bo[d]   (fp32 out)
// BM=128, BN=64 (MI=4, NI=2). grid (64, 4)
// ---------------------------------------------------------------------------
__global__ __launch_bounds__(256) void k_final(
    const short* __restrict__ Hmat, const short* __restrict__ Wob,
    const float* __restrict__ bo, float* __restrict__ out)
{
  __shared__ short As[128 * 64];
  __shared__ short Bs[64 * 64];
  const int bx = blockIdx.x, by = blockIdx.y;
  const short* Ag = Hmat + (size_t)bx * 128 * (NH * EH);
  const short* Bg = Wob  + (size_t)by * 64 * (NH * EH);

  f32x4_t acc[4][2] = {};
  gemm_core<4, 2>(Ag, NH * EH, Bg, NH * EH, NH * EH, As, Bs, acc);

  const int lane = threadIdx.x & 63, wv = threadIdx.x >> 6;
  const int wm = wv >> 1, wn = wv & 1, g = lane >> 4, r = lane & 15;
#pragma unroll
  for (int ni = 0; ni < 2; ++ni) {
    int d = by * 64 + wn * 32 + ni * 16 + r;
    float bia = bo[d];
#pragma unroll
    for (int mi = 0; mi < 4; ++mi) {
#pragma unroll
      for (int reg = 0; reg < 4; ++reg) {
        int m = bx * 128 + wm * 64 + mi * 16 + g * 4 + reg;
        out[(size_t)m * DIN + d] = acc[mi][ni][reg] + bia;
      }
    }
  }
}

// ---------------------------------------------------------------------------
extern "C" void kernel_launch(void* const* d_in, const int* in_sizes, int n_in,
                              void* d_out, int out_size, void* d_ws, size_t ws_size,
                              hipStream_t stream)
{
  const float* Q  = (const float*)d_in[0];
  const float* Wq = (const float*)d_in[1];
  const float* bq = (const float*)d_in[2];
  const float* Wk = (const float*)d_in[3];
  const float* bk = (const float*)d_in[4];
  const float* Wv = (const float*)d_in[5];
  const float* bv = (const float*)d_in[6];
  const float* Wo = (const float*)d_in[7];
  const float* bo = (const float*)d_in[8];
  float* out = (float*)d_out;

  // ---- workspace layout (bump allocator, 256B aligned) ----
  const size_t QB_B   = (size_t)T_SEQ * BATCH * DIN * 2;          //   4 MiB
  const size_t W_B    = (size_t)NH * EH * DIN * 2;                //   2 MiB each
  const size_t WO_B   = (size_t)DIN * NH * EH * 2;                //   2 MiB
  const size_t HMAT_B = (size_t)T_SEQ * BATCH * NH * EH * 2;      //  64 MiB
  const size_t QKV_B  = (size_t)BATCH * T_SEQ * EH * 2;           //   8 MiB / head
  const size_t P_B    = (size_t)BATCH * T_SEQ * T_SEQ * 2;        //  16 MiB / head
  const size_t INV_B  = (size_t)BATCH * T_SEQ * 4;
  const size_t CP_B   = (size_t)BATCH * 8 * T_SEQ * 4;

  const size_t fixedB  = QB_B + 3 * W_B + WO_B + HMAT_B;
  const size_t perHead = 4 * QKV_B + P_B + INV_B + CP_B;          // qb,kb,vb,vbT + P + inv + colpart

  int HG = 8;
  while (HG > 1 && fixedB + (size_t)HG * perHead + 65536 > ws_size) HG >>= 1;

  char* w = (char*)d_ws;
  auto alloc = [&](size_t bytes) {
    char* p = w;
    w += (bytes + 255) & ~(size_t)255;
    return p;
  };
  short* Qb   = (short*)alloc(QB_B);
  short* Wqb  = (short*)alloc(W_B);
  short* Wkb  = (short*)alloc(W_B);
  short* Wvb  = (short*)alloc(W_B);
  short* Wob  = (short*)alloc(WO_B);
  short* Hmat = (short*)alloc(HMAT_B);
  short* qb   = (short*)alloc((size_t)HG * QKV_B);
  short* kb   = (short*)alloc((size_t)HG * QKV_B);
  short* vb   = (short*)alloc((size_t)HG * QKV_B);
  short* vbT  = (short*)alloc((size_t)HG * QKV_B);
  short* Pbuf = (short*)alloc((size_t)HG * P_B);
  float* invs = (float*)alloc((size_t)HG * INV_B);
  float* cpart= (float*)alloc((size_t)HG * CP_B);

  // ---- K0: casts ----
  k_cvt<<<dim3(2048), 256, 0, stream>>>(Q,  Qb,  T_SEQ * BATCH * DIN / 4);
  k_cvt<<<dim3(1024), 256, 0, stream>>>(Wq, Wqb, NH * EH * DIN / 4);
  k_cvt<<<dim3(1024), 256, 0, stream>>>(Wk, Wkb, NH * EH * DIN / 4);
  k_cvt<<<dim3(1024), 256, 0, stream>>>(Wv, Wvb, NH * EH * DIN / 4);
  k_cvt<<<dim3(1024), 256, 0, stream>>>(Wo, Wob, DIN * NH * EH / 4);

  for (int h0 = 0; h0 < NH; h0 += HG) {
    k_proj  <<<dim3(64, 4, 3 * HG), 256, 0, stream>>>(Qb, Wqb, Wkb, Wvb, bq, bk, bv,
                                                      qb, kb, vb, h0, HG);
    k_pgen  <<<dim3(8, 8, HG * BATCH), 256, 0, stream>>>(qb, kb, Pbuf, cpart);
    k_invsum<<<dim3(HG * BATCH * T_SEQ / 256), 256, 0, stream>>>(cpart, invs, HG * BATCH);
    k_tr    <<<dim3(16, 8, HG * BATCH), 256, 0, stream>>>(vb, invs, vbT);
    k_ogemm <<<dim3(8, 4, HG * BATCH), 256, 0, stream>>>(Pbuf, vbT, Hmat, h0);
  }
  k_final<<<dim3(64, 4), 256, 0, stream>>>(Hmat, Wob, bo, out);
}